// Round 7
// baseline (162.559 us; speedup 1.0000x reference)
//
#include <hip/hip_runtime.h>

#define B_ 4
#define N_ 512
#define F_ 64
#define H_ 64
#define K_ 64
#define BN_ (B_*N_)
#define EPS_ 1e-14f
#define TSC 2.8853900817779268f   // 2*log2(e): tanh(x) = 1 - 2/(2^(x*TSC)+1)

typedef __attribute__((ext_vector_type(8))) short short8;
typedef __attribute__((ext_vector_type(4))) float f32x4;
typedef __attribute__((ext_vector_type(2))) float f32x2;

__device__ __forceinline__ unsigned short cvt_bf16(float f) {
    unsigned r;
    asm("v_cvt_pk_bf16_f32 %0, %1, %1" : "=v"(r) : "v"(f));
    return (unsigned short)r;
}
__device__ __forceinline__ unsigned cvt_pk_bf16(float lo, float hi) {
    unsigned r;
    asm("v_cvt_pk_bf16_f32 %0, %1, %2" : "=v"(r) : "v"(lo), "v"(hi));
    return r;
}
__device__ __forceinline__ float exp2_raw(float x) {   // single v_exp_f32 (2^x)
    float r;
    asm("v_exp_f32 %0, %1" : "=v"(r) : "v"(x));
    return r;
}
__device__ __forceinline__ float lane_bcast(float v, int lane) {
    return __int_as_float(__builtin_amdgcn_readlane(__float_as_int(v), lane));
}
__device__ __forceinline__ float rcpf(float x) { return __builtin_amdgcn_rcpf(x); }
__device__ __forceinline__ float fast_silu(float x) {
    return x * rcpf(1.0f + __expf(-x));
}

// ws (floats): PJ2[BN][64][2] ({ew(pre-scaled by TSC),es} interleaved) |
//              PI_EW[BN*64] | PI_ES[BN*64] | PJSA[BN] | PISA[BN]
#define W_PJ2  0
#define W_PIEW (BN_*128)
#define W_PIES (BN_*128 + BN_*64)
#define W_PJSA (BN_*128 + 2*BN_*64)
#define W_PISA (BN_*128 + 2*BN_*64 + BN_)

__global__ __launch_bounds__(256) void proj_kernel(
    const float* __restrict__ h, const float* __restrict__ W_ew,
    const float* __restrict__ W_sa, const float* __restrict__ W_es,
    float* __restrict__ ws)
{
    const int tid  = threadIdx.x;
    const int w    = tid >> 6;
    const int lane = tid & 63;
    const int node0 = blockIdx.x * 8;

    __shared__ float sW_ew[128][64];   // W_ew[f][t], f in [0,128)
    __shared__ float sW_es[128][64];   // W_es[1+f][t]
    __shared__ float sW_sa[128];
    __shared__ float sh[8][64];

    #pragma unroll
    for (int it = 0; it < 32; ++it) {
        const int idx = it*256 + tid;
        sW_ew[idx>>6][idx&63] = W_ew[idx];
        sW_es[idx>>6][idx&63] = W_es[64 + idx];   // skip row 0 of W_es
    }
    if (tid < 128) sW_sa[tid] = W_sa[tid];
    #pragma unroll
    for (int it = 0; it < 2; ++it) {
        const int idx = it*256 + tid;
        sh[idx>>6][idx&63] = h[node0*F_ + idx];
    }
    __syncthreads();

    const int n0 = w*2;                 // two nodes per wave
    float jew0=0.f,iew0=0.f,jes0=0.f,ies0=0.f;
    float jew1=0.f,iew1=0.f,jes1=0.f,ies1=0.f;
    #pragma unroll 8
    for (int f = 0; f < 64; ++f) {
        const float wje = sW_ew[f][lane],    wie = sW_ew[64+f][lane];
        const float wjs = sW_es[f][lane],    wis = sW_es[64+f][lane];
        const float h0  = sh[n0][f],         h1  = sh[n0+1][f];
        jew0 = fmaf(h0, wje, jew0);  iew0 = fmaf(h0, wie, iew0);
        jes0 = fmaf(h0, wjs, jes0);  ies0 = fmaf(h0, wis, ies0);
        jew1 = fmaf(h1, wje, jew1);  iew1 = fmaf(h1, wie, iew1);
        jes1 = fmaf(h1, wjs, jes1);  ies1 = fmaf(h1, wis, ies1);
    }
    // W_sa projections: lane-parallel over f, shuffle-reduce
    float p0 = sh[n0][lane]   * sW_sa[lane];
    float q0 = sh[n0][lane]   * sW_sa[64+lane];
    float p1 = sh[n0+1][lane] * sW_sa[lane];
    float q1 = sh[n0+1][lane] * sW_sa[64+lane];
    #pragma unroll
    for (int m = 32; m >= 1; m >>= 1) {
        p0 += __shfl_xor(p0, m, 64);  q0 += __shfl_xor(q0, m, 64);
        p1 += __shfl_xor(p1, m, 64);  q1 += __shfl_xor(q1, m, 64);
    }

    const int g0 = node0 + n0;
    const int g1 = g0 + 1;
    ws[W_PJ2 + (size_t)g0*128 + lane*2 + 0] = jew0 * TSC;  // pre-scaled for tanh
    ws[W_PJ2 + (size_t)g0*128 + lane*2 + 1] = jes0;
    ws[W_PJ2 + (size_t)g1*128 + lane*2 + 0] = jew1 * TSC;
    ws[W_PJ2 + (size_t)g1*128 + lane*2 + 1] = jes1;
    ws[W_PIEW + g0*K_ + lane] = iew0;
    ws[W_PIEW + g1*K_ + lane] = iew1;
    ws[W_PIES + g0*H_ + lane] = ies0;
    ws[W_PIES + g1*H_ + lane] = ies1;
    if (lane == 0) {
        ws[W_PJSA + g0] = p0;  ws[W_PISA + g0] = q0;
        ws[W_PJSA + g1] = p1;  ws[W_PISA + g1] = q1;
    }
}

// R7: 2 nodes (i) per block -> 1024 blocks = 4 blocks/CU, exactly matching
// (256,4) residency (proven no-spill, 128-reg budget). Single full-residency
// round, no ragged tail (R6's 8-blocks-at-5-residency averaged 43% occ).
// Shared per-jj loads (pj, addressing) amortize over both i's.
// LDS: he_buf 2*9216 + sdA 2*4096 + coord 2*1024 + WT 8192 + s_bw 512
//    = 37376 B -> 4 blocks/CU = 149.5 KB <= 160 KB.  Epilogue aliased into
// he_buf (4608 floats), fenced by barrier.
// Spill tripwire: FETCH_SIZE must stay ~6 MB.
__global__ __launch_bounds__(256, 4) void main_kernel(
    const float* __restrict__ h, const float* __restrict__ x,
    const float* __restrict__ b_ew, const float* __restrict__ b_es,
    const float* __restrict__ W_es, const float* __restrict__ W_c1,
    const float* __restrict__ b_c1, const float* __restrict__ W_c2,
    const float* __restrict__ b_c2, const float* __restrict__ W_n,
    const float* __restrict__ b_n,
    const float* __restrict__ ws, float* __restrict__ out)
{
    const int bi0  = blockIdx.x * 2;      // first node
    const int bi1  = bi0 + 1;             // second node (same batch: N even)
    const int b    = bi0 >> 9;
    const int base = b * N_;
    const int tid  = threadIdx.x;
    const int w    = tid >> 6;            // wave 0..3
    const int lane = tid & 63;
    const int quad = lane >> 4;
    const int l16  = lane & 15;

    __shared__ unsigned short he_buf[2][4][16][72];  // per-i bf16 he subtiles
    __shared__ float sdA[2][4][64][4];    // per-i {v0,v1,v2,filt} per j
    __shared__ float coord_buf[2][4][64];
    // W_c1^T as bf16, XOR-swizzled: element (k,col) at byte col*128 + (2k ^ ((col&7)<<4))
    __shared__ unsigned short WT[64*64];
    __shared__ float s_bw[64][2];         // {b_c1, W_c2} pairs

    // epilogue aliases into he_buf (dead after main loop, fenced by barrier):
    float* const epi = (float*)&he_buf[0][0][0][0];   // 4608 floats
#define S_ATT(ii,cmp,wv,ln) epi[(ii)*768 + (cmp)*256 + (wv)*64 + (ln)]
#define S_HEA(ii,wv,ln)     epi[1536 + (ii)*256 + (wv)*64 + (ln)]
#define S_MISC(ii,wv,k)     epi[2048 + (ii)*16 + (wv)*4 + (k)]
#define S_CONCAT(ii,m)      epi[2080 + (ii)*192 + (m)]
#define S_HNEW(ii,hf,ln)    epi[2464 + (ii)*128 + (hf)*64 + (ln)]

    // ---- stage W_c1 into LDS (shared by all waves) ----
    {
        const int col = tid & 63;
        const int k0  = (tid >> 6) * 16;
        const unsigned swz = (col & 7) << 4;
        #pragma unroll
        for (int m = 0; m < 8; ++m) {
            const int k = k0 + 2*m;
            const float f0 = W_c1[k*H_ + col];
            const float f1 = W_c1[(k+1)*H_ + col];
            *(unsigned*)((char*)WT + (col*128 + ((2*k) ^ swz))) = cvt_pk_bf16(f0, f1);
        }
        if (tid < 64) { s_bw[tid][0] = b_c1[tid]; s_bw[tid][1] = W_c2[tid]; }
    }

    const float pi_ew0 = (ws[W_PIEW + bi0*K_ + lane] + b_ew[lane]) * TSC;
    const float pi_ew1 = (ws[W_PIEW + bi1*K_ + lane] + b_ew[lane]) * TSC;
    const float pi_es0 = ws[W_PIES + bi0*H_ + lane] + b_es[lane];
    const float pi_es1 = ws[W_PIES + bi1*H_ + lane] + b_es[lane];
    const float pisa0  = ws[W_PISA + bi0];
    const float pisa1  = ws[W_PISA + bi1];
    const float xi00 = x[bi0*3+0], xi01 = x[bi0*3+1], xi02 = x[bi0*3+2];
    const float xi10 = x[bi1*3+0], xi11 = x[bi1*3+1], xi12 = x[bi1*3+2];
    const float wes0_t = W_es[lane];
    const float bc2    = b_c2[0];

    // per-lane swizzled byte offsets of the two B-fragments (kc=0,1) in WT
    const unsigned swzl = (l16 & 7) << 4;
    const unsigned offB0 = (unsigned)l16*128 + (((unsigned)quad*16) ^ swzl);
    const unsigned offB1 = (unsigned)l16*128 + ((64u + (unsigned)quad*16) ^ swzl);

    __syncthreads();   // WT + s_bw ready

    float att00=0.f, att01=0.f, att02=0.f, hea0=0.f, sume0=0.f;
    float att10=0.f, att11=0.f, att12=0.f, hea1=0.f, sume1=0.f;
    float xa00=0.f, xa01=0.f, xa02=0.f;
    float xa10=0.f, xa11=0.f, xa12=0.f;

    for (int c = 0; c < 2; ++c) {
        const int j0 = (w*2 + c) * 64;

        // ---- phase A: per-j scalars for both i's (lane = jj over 64) ----
        float esem0, esem1;
        {
            const int gj = base + j0 + lane;
            const float xj0 = x[gj*3+0], xj1 = x[gj*3+1], xj2 = x[gj*3+2];
            const float pjsa = ws[W_PJSA + gj];
            {   // i = bi0
                const float d0 = xj0-xi00, d1 = xj1-xi01, d2 = xj2-xi02;
                const float d2s = fmaf(d0,d0, fmaf(d1,d1, d2*d2));
                const float nrm = sqrtf(d2s + EPS_);
                const float e   = __expf(nrm);
                sume0 += e;
                const float filt = rcpf(nrm + 0.1f);
                const float inv  = rcpf(fmaf(nrm, nrm, EPS_));
                const float sv   = pjsa + pisa0;
                const float sem  = (sv >= 0.f) ? sv : 0.01f*sv;
                esem0 = e * sem;
                f32x4 p = { d0*inv, d1*inv, d2*inv, filt };
                *(f32x4*)&sdA[0][w][lane][0] = p;
            }
            {   // i = bi1
                const float d0 = xj0-xi10, d1 = xj1-xi11, d2 = xj2-xi12;
                const float d2s = fmaf(d0,d0, fmaf(d1,d1, d2*d2));
                const float nrm = sqrtf(d2s + EPS_);
                const float e   = __expf(nrm);
                sume1 += e;
                const float filt = rcpf(nrm + 0.1f);
                const float inv  = rcpf(fmaf(nrm, nrm, EPS_));
                const float sv   = pjsa + pisa1;
                const float sem  = (sv >= 0.f) ? sv : 0.01f*sv;
                esem1 = e * sem;
                f32x4 p = { d0*inv, d1*inv, d2*inv, filt };
                *(f32x4*)&sdA[1][w][lane][0] = p;
            }
        }

        // four 16-j subchunks: phase B fills he subtiles, phase C MFMAs them
        #pragma unroll
        for (int s = 0; s < 4; ++s) {
            const int sj = s*16;
            const float* pjp = ws + W_PJ2 + (size_t)(base + j0 + sj)*128 + lane*2;
            #pragma unroll 2
            for (int jj = 0; jj < 16; ++jj) {
                const f32x2 pj = *(const f32x2*)(pjp + (size_t)jj*128);   // shared
                const f32x4 p0 = *(const f32x4*)&sdA[0][w][sj + jj][0];
                const f32x4 p1 = *(const f32x4*)&sdA[1][w][sj + jj][0];
                const float es0 = lane_bcast(esem0, sj + jj);
                const float es1 = lane_bcast(esem1, sj + jj);
                {   // i = bi0
                    const float pre = fmaf(p0.w, wes0_t, pj.y + pi_es0);
                    const float he  = fast_silu(pre);
                    hea0 = fmaf(es0, he, hea0);
                    he_buf[0][w][jj][lane] = cvt_bf16(he);
                    const float ewt = fmaf(-2.0f, rcpf(exp2_raw(pj.x + pi_ew0) + 1.0f), 1.0f);
                    att00 = fmaf(ewt, p0.x, att00);
                    att01 = fmaf(ewt, p0.y, att01);
                    att02 = fmaf(ewt, p0.z, att02);
                }
                {   // i = bi1
                    const float pre = fmaf(p1.w, wes0_t, pj.y + pi_es1);
                    const float he  = fast_silu(pre);
                    hea1 = fmaf(es1, he, hea1);
                    he_buf[1][w][jj][lane] = cvt_bf16(he);
                    const float ewt = fmaf(-2.0f, rcpf(exp2_raw(pj.x + pi_ew1) + 1.0f), 1.0f);
                    att10 = fmaf(ewt, p1.x, att10);
                    att11 = fmaf(ewt, p1.y, att11);
                    att12 = fmaf(ewt, p1.z, att12);
                }
            }

            // ---- phase C: coord MLP via MFMA, per i ----
            #pragma unroll
            for (int ii = 0; ii < 2; ++ii) {
                const short8 a0 = *(const short8*)&he_buf[ii][w][l16][quad*8];
                const short8 a1 = *(const short8*)&he_buf[ii][w][l16][32 + quad*8];
                float rs0=0.f, rs1=0.f, rs2=0.f, rs3=0.f;
                #pragma unroll
                for (int nt = 0; nt < 4; ++nt) {
                    const short8 b0 = *(const short8*)((const char*)WT + (nt*2048 + offB0));
                    const short8 b1 = *(const short8*)((const char*)WT + (nt*2048 + offB1));
                    const f32x2 bw = *(const f32x2*)&s_bw[nt*16 + l16][0];
                    f32x4 acc = {0.f, 0.f, 0.f, 0.f};
                    acc = __builtin_amdgcn_mfma_f32_16x16x32_bf16(a0, b0, acc, 0, 0, 0);
                    acc = __builtin_amdgcn_mfma_f32_16x16x32_bf16(a1, b1, acc, 0, 0, 0);
                    rs0 += fast_silu(acc[0] + bw.x) * bw.y;
                    rs1 += fast_silu(acc[1] + bw.x) * bw.y;
                    rs2 += fast_silu(acc[2] + bw.x) * bw.y;
                    rs3 += fast_silu(acc[3] + bw.x) * bw.y;
                }
                #pragma unroll
                for (int m = 1; m <= 8; m <<= 1) {      // reduce over cols (l16)
                    rs0 += __shfl_xor(rs0, m, 64);
                    rs1 += __shfl_xor(rs1, m, 64);
                    rs2 += __shfl_xor(rs2, m, 64);
                    rs3 += __shfl_xor(rs3, m, 64);
                }
                if (l16 == 0) {
                    f32x4 cv = { rs0 + bc2, rs1 + bc2, rs2 + bc2, rs3 + bc2 };
                    *(f32x4*)&coord_buf[ii][w][sj + quad*4] = cv;
                }
            }
        }

        // ---- phase D: xa += d * coord (x re-loaded, L1-hot; d not carried) ----
        {
            const int gj = base + j0 + lane;
            const float xj0 = x[gj*3+0], xj1 = x[gj*3+1], xj2 = x[gj*3+2];
            const float cj0 = coord_buf[0][w][lane];
            const float cj1 = coord_buf[1][w][lane];
            xa00 = fmaf(xj0-xi00, cj0, xa00);
            xa01 = fmaf(xj1-xi01, cj0, xa01);
            xa02 = fmaf(xj2-xi02, cj0, xa02);
            xa10 = fmaf(xj0-xi10, cj1, xa10);
            xa11 = fmaf(xj1-xi11, cj1, xa11);
            xa12 = fmaf(xj2-xi12, cj1, xa12);
        }
    }

    __syncthreads();   // all waves done with he_buf before epilogue aliasing

    // wave-level reduce of j-lane partials (both i's)
    #pragma unroll
    for (int m = 32; m >= 1; m >>= 1) {
        sume0 += __shfl_xor(sume0, m, 64);
        xa00  += __shfl_xor(xa00,  m, 64);
        xa01  += __shfl_xor(xa01,  m, 64);
        xa02  += __shfl_xor(xa02,  m, 64);
        sume1 += __shfl_xor(sume1, m, 64);
        xa10  += __shfl_xor(xa10,  m, 64);
        xa11  += __shfl_xor(xa11,  m, 64);
        xa12  += __shfl_xor(xa12,  m, 64);
    }
    S_ATT(0,0,w,lane) = att00;  S_ATT(0,1,w,lane) = att01;  S_ATT(0,2,w,lane) = att02;
    S_ATT(1,0,w,lane) = att10;  S_ATT(1,1,w,lane) = att11;  S_ATT(1,2,w,lane) = att12;
    S_HEA(0,w,lane) = hea0;     S_HEA(1,w,lane) = hea1;
    if (lane == 0) {
        S_MISC(0,w,0) = sume0; S_MISC(0,w,1) = xa00; S_MISC(0,w,2) = xa01; S_MISC(0,w,3) = xa02;
        S_MISC(1,w,0) = sume1; S_MISC(1,w,1) = xa10; S_MISC(1,w,2) = xa11; S_MISC(1,w,3) = xa12;
    }
    __syncthreads();

    if ((w & 1) == 0) {               // w=0 -> i=bi0, w=2 -> i=bi1
        const int ii = w >> 1;
        const int biX = bi0 + ii;
        const float a0 = S_ATT(ii,0,0,lane)+S_ATT(ii,0,1,lane)+S_ATT(ii,0,2,lane)+S_ATT(ii,0,3,lane);
        const float a1 = S_ATT(ii,1,0,lane)+S_ATT(ii,1,1,lane)+S_ATT(ii,1,2,lane)+S_ATT(ii,1,3,lane);
        const float a2 = S_ATT(ii,2,0,lane)+S_ATT(ii,2,1,lane)+S_ATT(ii,2,2,lane)+S_ATT(ii,2,3,lane);
        const float hg = S_HEA(ii,0,lane)+S_HEA(ii,1,lane)+S_HEA(ii,2,lane)+S_HEA(ii,3,lane);
        const float se = S_MISC(ii,0,0)+S_MISC(ii,1,0)+S_MISC(ii,2,0)+S_MISC(ii,3,0);
        const float attn = sqrtf(fmaf(a0,a0, fmaf(a1,a1, a2*a2)) + EPS_);
        S_CONCAT(ii, lane)       = h[biX*F_ + lane];
        S_CONCAT(ii, 64 + lane)  = hg * rcpf(se);
        S_CONCAT(ii, 128 + lane) = attn;
        if (lane < 3) {
            const float xat = S_MISC(ii,0,1+lane)+S_MISC(ii,1,1+lane)+S_MISC(ii,2,1+lane)+S_MISC(ii,3,1+lane);
            out[(size_t)BN_*H_ + biX*3 + lane] = x[biX*3+lane] + xat;   // x_new
        }
    }
    __syncthreads();

    // output GEMV: 4 waves = 2 i's x 2 halves of 96 rows each
    {
        const int ii = w >> 1, hf = w & 1;
        float acc = 0.f;
        const int m0 = hf * 96;
        #pragma unroll 8
        for (int m = m0; m < m0 + 96; ++m)
            acc = fmaf(S_CONCAT(ii, m), W_n[m*H_ + lane], acc);
        S_HNEW(ii, hf, lane) = acc;
    }
    __syncthreads();
    if (w < 2) {
        out[(bi0 + w)*H_ + lane] = S_HNEW(w,0,lane) + S_HNEW(w,1,lane) + b_n[lane];  // h_new
    }
}

extern "C" void kernel_launch(void* const* d_in, const int* in_sizes, int n_in,
                              void* d_out, int out_size, void* d_ws, size_t ws_size,
                              hipStream_t stream) {
    (void)in_sizes; (void)n_in; (void)out_size; (void)ws_size;
    const float* h    = (const float*)d_in[0];
    const float* x    = (const float*)d_in[1];
    const float* W_ew = (const float*)d_in[2];
    const float* b_ew = (const float*)d_in[3];
    const float* W_sa = (const float*)d_in[4];
    const float* W_es = (const float*)d_in[5];
    const float* b_es = (const float*)d_in[6];
    const float* W_c1 = (const float*)d_in[7];
    const float* b_c1 = (const float*)d_in[8];
    const float* W_c2 = (const float*)d_in[9];
    const float* b_c2 = (const float*)d_in[10];
    const float* W_n  = (const float*)d_in[11];
    const float* b_n  = (const float*)d_in[12];
    float* out = (float*)d_out;
    float* ws  = (float*)d_ws;

    proj_kernel<<<dim3(BN_/8), dim3(256), 0, stream>>>(h, W_ew, W_sa, W_es, ws);
    main_kernel<<<dim3(BN_/2), dim3(256), 0, stream>>>(h, x, b_ew, b_es, W_es, W_c1,
                                                       b_c1, W_c2, b_c2, W_n, b_n, ws, out);
}

// Round 9
// 155.843 us; speedup vs baseline: 1.0431x; 1.0431x over previous
//
#include <hip/hip_runtime.h>

#define B_ 4
#define N_ 512
#define F_ 64
#define H_ 64
#define K_ 64
#define BN_ (B_*N_)
#define EPS_ 1e-14f
#define TSC 2.8853900817779268f   // 2*log2(e): tanh(x) = 1 - 2/(2^(x*TSC)+1)

typedef __attribute__((ext_vector_type(8))) short short8;
typedef __attribute__((ext_vector_type(4))) float f32x4;
typedef __attribute__((ext_vector_type(2))) float f32x2;

__device__ __forceinline__ unsigned short cvt_bf16(float f) {
    unsigned r;
    asm("v_cvt_pk_bf16_f32 %0, %1, %1" : "=v"(r) : "v"(f));
    return (unsigned short)r;
}
__device__ __forceinline__ unsigned cvt_pk_bf16(float lo, float hi) {
    unsigned r;
    asm("v_cvt_pk_bf16_f32 %0, %1, %2" : "=v"(r) : "v"(lo), "v"(hi));
    return r;
}
__device__ __forceinline__ float exp2_raw(float x) {   // single v_exp_f32 (2^x)
    float r;
    asm("v_exp_f32 %0, %1" : "=v"(r) : "v"(x));
    return r;
}
__device__ __forceinline__ float lane_bcast(float v, int lane) {
    return __int_as_float(__builtin_amdgcn_readlane(__float_as_int(v), lane));
}
__device__ __forceinline__ float rcpf(float x) { return __builtin_amdgcn_rcpf(x); }
__device__ __forceinline__ float fast_silu(float x) {
    return x * rcpf(1.0f + __expf(-x));
}

// ws (floats): PJ2[BN][64][2] ({ew(pre-scaled by TSC),es} interleaved) |
//              PI_EW[BN*64] | PI_ES[BN*64] | PJSA[BN] | PISA[BN]
#define W_PJ2  0
#define W_PIEW (BN_*128)
#define W_PIES (BN_*128 + BN_*64)
#define W_PJSA (BN_*128 + 2*BN_*64)
#define W_PISA (BN_*128 + 2*BN_*64 + BN_)

__global__ __launch_bounds__(256) void proj_kernel(
    const float* __restrict__ h, const float* __restrict__ W_ew,
    const float* __restrict__ W_sa, const float* __restrict__ W_es,
    float* __restrict__ ws)
{
    const int tid  = threadIdx.x;
    const int w    = tid >> 6;
    const int lane = tid & 63;
    const int node0 = blockIdx.x * 8;

    __shared__ float sW_ew[128][64];   // W_ew[f][t], f in [0,128)
    __shared__ float sW_es[128][64];   // W_es[1+f][t]
    __shared__ float sW_sa[128];
    __shared__ float sh[8][64];

    #pragma unroll
    for (int it = 0; it < 32; ++it) {
        const int idx = it*256 + tid;
        sW_ew[idx>>6][idx&63] = W_ew[idx];
        sW_es[idx>>6][idx&63] = W_es[64 + idx];   // skip row 0 of W_es
    }
    if (tid < 128) sW_sa[tid] = W_sa[tid];
    #pragma unroll
    for (int it = 0; it < 2; ++it) {
        const int idx = it*256 + tid;
        sh[idx>>6][idx&63] = h[node0*F_ + idx];
    }
    __syncthreads();

    const int n0 = w*2;                 // two nodes per wave
    float jew0=0.f,iew0=0.f,jes0=0.f,ies0=0.f;
    float jew1=0.f,iew1=0.f,jes1=0.f,ies1=0.f;
    #pragma unroll 8
    for (int f = 0; f < 64; ++f) {
        const float wje = sW_ew[f][lane],    wie = sW_ew[64+f][lane];
        const float wjs = sW_es[f][lane],    wis = sW_es[64+f][lane];
        const float h0  = sh[n0][f],         h1  = sh[n0+1][f];
        jew0 = fmaf(h0, wje, jew0);  iew0 = fmaf(h0, wie, iew0);
        jes0 = fmaf(h0, wjs, jes0);  ies0 = fmaf(h0, wis, ies0);
        jew1 = fmaf(h1, wje, jew1);  iew1 = fmaf(h1, wie, iew1);
        jes1 = fmaf(h1, wjs, jes1);  ies1 = fmaf(h1, wis, ies1);
    }
    // W_sa projections: lane-parallel over f, shuffle-reduce
    float p0 = sh[n0][lane]   * sW_sa[lane];
    float q0 = sh[n0][lane]   * sW_sa[64+lane];
    float p1 = sh[n0+1][lane] * sW_sa[lane];
    float q1 = sh[n0+1][lane] * sW_sa[64+lane];
    #pragma unroll
    for (int m = 32; m >= 1; m >>= 1) {
        p0 += __shfl_xor(p0, m, 64);  q0 += __shfl_xor(q0, m, 64);
        p1 += __shfl_xor(p1, m, 64);  q1 += __shfl_xor(q1, m, 64);
    }

    const int g0 = node0 + n0;
    const int g1 = g0 + 1;
    ws[W_PJ2 + (size_t)g0*128 + lane*2 + 0] = jew0 * TSC;  // pre-scaled for tanh
    ws[W_PJ2 + (size_t)g0*128 + lane*2 + 1] = jes0;
    ws[W_PJ2 + (size_t)g1*128 + lane*2 + 0] = jew1 * TSC;
    ws[W_PJ2 + (size_t)g1*128 + lane*2 + 1] = jes1;
    ws[W_PIEW + g0*K_ + lane] = iew0;
    ws[W_PIEW + g1*K_ + lane] = iew1;
    ws[W_PIES + g0*H_ + lane] = ies0;
    ws[W_PIES + g1*H_ + lane] = ies1;
    if (lane == 0) {
        ws[W_PJSA + g0] = p0;  ws[W_PISA + g0] = q0;
        ws[W_PJSA + g1] = p1;  ws[W_PISA + g1] = q1;
    }
}

// R9: R6 structure (1 node/block, minw=5 — best measured, main 86.6 us) +
// v_pk_add_f32 forming BOTH activation args in one op ({pj.x,pj.y} +
// {pi_ew',pi_es}; both sources are natural VGPR pairs).  The R8 pk_fma is
// dropped: VOP3P requires pair operands, broadcasting ewt needs a v_mov,
// making it net-zero vs 2 scalar FMAs.
// Ledger recap: minw=6 spills (arch grant 40 < live ~44-48); minw=5 grants 48,
// no spill, 5 waves/SIMD.  2-i/block (R7) forced minw=4 -> slower.
// LDS: he_buf 9216 + sdA 4096 + coord 1024 + WT 8192 + s_bw 512 = 23040 B.
// Spill tripwire: FETCH_SIZE must stay ~5.5 MB.
__global__ __launch_bounds__(256, 5) void main_kernel(
    const float* __restrict__ h, const float* __restrict__ x,
    const float* __restrict__ b_ew, const float* __restrict__ b_es,
    const float* __restrict__ W_es, const float* __restrict__ W_c1,
    const float* __restrict__ b_c1, const float* __restrict__ W_c2,
    const float* __restrict__ b_c2, const float* __restrict__ W_n,
    const float* __restrict__ b_n,
    const float* __restrict__ ws, float* __restrict__ out)
{
    const int bi   = blockIdx.x;          // b*N + i
    const int b    = bi >> 9;
    const int base = b * N_;
    const int tid  = threadIdx.x;
    const int w    = tid >> 6;            // wave 0..3
    const int lane = tid & 63;
    const int quad = lane >> 4;
    const int l16  = lane & 15;

    __shared__ unsigned short he_buf[4][16][72];  // bf16 he subtile; epilogue aliases
    __shared__ float sdA[4][64][4];       // {v0,v1,v2,filt} per j
    __shared__ float coord_buf[4][64];
    // W_c1^T as bf16, XOR-swizzled: element (k,col) at byte col*128 + (2k ^ ((col&7)<<4))
    __shared__ unsigned short WT[64*64];
    __shared__ float s_bw[64][2];         // {b_c1, W_c2} pairs

    // epilogue aliases into he_buf (dead after main loop, fenced by barrier):
    float* const epi = (float*)&he_buf[0][0][0];   // 2304 floats available
#define S_ATT(cmp, wv, ln) epi[(cmp)*256 + (wv)*64 + (ln)]
#define S_HEA(wv, ln)      epi[768 + (wv)*64 + (ln)]
#define S_MISC(wv, k)      epi[1024 + (wv)*4 + (k)]
#define S_CONCAT(m)        epi[1040 + (m)]
#define S_HNEW(wv, ln)     epi[1240 + (wv)*64 + (ln)]

    // ---- stage W_c1 into LDS (shared by all 4 waves) ----
    {
        const int col = tid & 63;
        const int k0  = (tid >> 6) * 16;
        const unsigned swz = (col & 7) << 4;
        #pragma unroll
        for (int m = 0; m < 8; ++m) {
            const int k = k0 + 2*m;
            const float f0 = W_c1[k*H_ + col];
            const float f1 = W_c1[(k+1)*H_ + col];
            *(unsigned*)((char*)WT + (col*128 + ((2*k) ^ swz))) = cvt_pk_bf16(f0, f1);
        }
        if (tid < 64) { s_bw[tid][0] = b_c1[tid]; s_bw[tid][1] = W_c2[tid]; }
    }

    const float pi_ew_t = (ws[W_PIEW + bi*K_ + lane] + b_ew[lane]) * TSC;
    const float pi_es_t = ws[W_PIES + bi*H_ + lane] + b_es[lane];
    const f32x2 pi_pack = { pi_ew_t, pi_es_t };   // matches pj order {x=ew', y=es}
    const float pisa    = ws[W_PISA + bi];
    const float xi0 = x[bi*3+0], xi1 = x[bi*3+1], xi2 = x[bi*3+2];
    const float wes0_t = W_es[lane];
    const float bc2    = b_c2[0];

    // per-lane swizzled byte offsets of the two B-fragments (kc=0,1) in WT
    const unsigned swzl = (l16 & 7) << 4;
    const unsigned offB0 = (unsigned)l16*128 + (((unsigned)quad*16) ^ swzl);
    const unsigned offB1 = (unsigned)l16*128 + ((64u + (unsigned)quad*16) ^ swzl);

    __syncthreads();   // WT + s_bw ready

    float att0=0.f, att1=0.f, att2=0.f, hea=0.f, sume=0.f;
    float xa0=0.f, xa1=0.f, xa2=0.f;

    for (int c = 0; c < 2; ++c) {
        const int j0 = (w*2 + c) * 64;

        // ---- phase A: per-j scalars (lane = jj over 64) ----
        float esem, d0, d1, d2;
        {
            const int gj = base + j0 + lane;
            d0 = x[gj*3+0] - xi0;
            d1 = x[gj*3+1] - xi1;
            d2 = x[gj*3+2] - xi2;
            const float d2s = fmaf(d0,d0, fmaf(d1,d1, d2*d2));
            const float nrm = sqrtf(d2s + EPS_);
            const float e   = __expf(nrm);
            sume += e;
            const float filt = rcpf(nrm + 0.1f);
            const float inv  = rcpf(fmaf(nrm, nrm, EPS_));
            const float sv   = ws[W_PJSA + gj] + pisa;
            const float sem  = (sv >= 0.f) ? sv : 0.01f*sv;
            esem = e * sem;
            f32x4 p0 = { d0*inv, d1*inv, d2*inv, filt };
            *(f32x4*)&sdA[w][lane][0] = p0;
        }

        // four 16-j subchunks: phase B fills he subtile, phase C MFMAs it
        #pragma unroll
        for (int s = 0; s < 4; ++s) {
            const int sj = s*16;
            const float* pjp = ws + W_PJ2 + (size_t)(base + j0 + sj)*128 + lane*2;
            #pragma unroll 4
            for (int jj = 0; jj < 16; ++jj) {
                const f32x2 pj = *(const f32x2*)(pjp + (size_t)jj*128);
                const f32x4 p0 = *(const f32x4*)&sdA[w][sj + jj][0];   // broadcast
                const float esem_s = lane_bcast(esem, sj + jj);
                // one packed add forms both activation args:
                //   args.x = pj.x + pi_ew' (tanh, pre-scaled); args.y = pj.y + pi_es
                f32x2 args;
                asm("v_pk_add_f32 %0, %1, %2" : "=v"(args) : "v"(pj), "v"(pi_pack));
                const float pre = fmaf(p0.w, wes0_t, args.y);
                const float he  = fast_silu(pre);
                hea = fmaf(esem_s, he, hea);
                he_buf[w][jj][lane] = cvt_bf16(he);
                // tanh with pre-scaled argument: 1 - 2/(2^(x') + 1)
                const float ewt = fmaf(-2.0f, rcpf(exp2_raw(args.x) + 1.0f), 1.0f);
                att0 = fmaf(ewt, p0.x, att0);
                att1 = fmaf(ewt, p0.y, att1);
                att2 = fmaf(ewt, p0.z, att2);
            }

            // ---- phase C: coord MLP via MFMA on the 16-row subtile ----
            {
                const short8 a0 = *(const short8*)&he_buf[w][l16][quad*8];
                const short8 a1 = *(const short8*)&he_buf[w][l16][32 + quad*8];
                float rs0=0.f, rs1=0.f, rs2=0.f, rs3=0.f;
                #pragma unroll
                for (int nt = 0; nt < 4; ++nt) {
                    const short8 b0 = *(const short8*)((const char*)WT + (nt*2048 + offB0));
                    const short8 b1 = *(const short8*)((const char*)WT + (nt*2048 + offB1));
                    const f32x2 bw = *(const f32x2*)&s_bw[nt*16 + l16][0];
                    f32x4 acc = {0.f, 0.f, 0.f, 0.f};
                    acc = __builtin_amdgcn_mfma_f32_16x16x32_bf16(a0, b0, acc, 0, 0, 0);
                    acc = __builtin_amdgcn_mfma_f32_16x16x32_bf16(a1, b1, acc, 0, 0, 0);
                    rs0 += fast_silu(acc[0] + bw.x) * bw.y;
                    rs1 += fast_silu(acc[1] + bw.x) * bw.y;
                    rs2 += fast_silu(acc[2] + bw.x) * bw.y;
                    rs3 += fast_silu(acc[3] + bw.x) * bw.y;
                }
                #pragma unroll
                for (int m = 1; m <= 8; m <<= 1) {      // reduce over cols (l16)
                    rs0 += __shfl_xor(rs0, m, 64);
                    rs1 += __shfl_xor(rs1, m, 64);
                    rs2 += __shfl_xor(rs2, m, 64);
                    rs3 += __shfl_xor(rs3, m, 64);
                }
                if (l16 == 0) {
                    f32x4 cv = { rs0 + bc2, rs1 + bc2, rs2 + bc2, rs3 + bc2 };
                    *(f32x4*)&coord_buf[w][sj + quad*4] = cv;
                }
            }
        }

        // ---- phase D: xa += d * coord (lane = jj over 64) ----
        {
            const float cj = coord_buf[w][lane];
            xa0 = fmaf(d0, cj, xa0);
            xa1 = fmaf(d1, cj, xa1);
            xa2 = fmaf(d2, cj, xa2);
        }
    }

    __syncthreads();   // all waves done with he_buf before epilogue aliasing

    // wave-level reduce of j-lane partials
    #pragma unroll
    for (int m = 32; m >= 1; m >>= 1) {
        sume += __shfl_xor(sume, m, 64);
        xa0  += __shfl_xor(xa0,  m, 64);
        xa1  += __shfl_xor(xa1,  m, 64);
        xa2  += __shfl_xor(xa2,  m, 64);
    }
    S_ATT(0, w, lane) = att0;
    S_ATT(1, w, lane) = att1;
    S_ATT(2, w, lane) = att2;
    S_HEA(w, lane)    = hea;
    if (lane == 0) {
        S_MISC(w, 0) = sume; S_MISC(w, 1) = xa0; S_MISC(w, 2) = xa1; S_MISC(w, 3) = xa2;
    }
    __syncthreads();

    if (w == 0) {
        const float a0 = S_ATT(0,0,lane)+S_ATT(0,1,lane)+S_ATT(0,2,lane)+S_ATT(0,3,lane);
        const float a1 = S_ATT(1,0,lane)+S_ATT(1,1,lane)+S_ATT(1,2,lane)+S_ATT(1,3,lane);
        const float a2 = S_ATT(2,0,lane)+S_ATT(2,1,lane)+S_ATT(2,2,lane)+S_ATT(2,3,lane);
        const float hg = S_HEA(0,lane)+S_HEA(1,lane)+S_HEA(2,lane)+S_HEA(3,lane);
        const float se = S_MISC(0,0)+S_MISC(1,0)+S_MISC(2,0)+S_MISC(3,0);
        const float attn = sqrtf(fmaf(a0,a0, fmaf(a1,a1, a2*a2)) + EPS_);
        S_CONCAT(lane)       = h[bi*F_ + lane];
        S_CONCAT(64 + lane)  = hg * rcpf(se);
        S_CONCAT(128 + lane) = attn;
    }
    if (tid < 3) {
        const float xat = S_MISC(0,1+tid)+S_MISC(1,1+tid)+S_MISC(2,1+tid)+S_MISC(3,1+tid);
        out[(size_t)BN_*H_ + bi*3 + tid] = x[bi*3+tid] + xat;       // x_new
    }
    __syncthreads();

    // output GEMV split across 4 waves (48 rows each)
    {
        float acc = 0.f;
        const int m0 = w * 48;
        #pragma unroll 8
        for (int m = m0; m < m0 + 48; ++m)
            acc = fmaf(S_CONCAT(m), W_n[m*H_ + lane], acc);
        S_HNEW(w, lane) = acc;
    }
    __syncthreads();
    if (w == 0) {
        out[bi*H_ + lane] = S_HNEW(0,lane) + S_HNEW(1,lane)
                          + S_HNEW(2,lane) + S_HNEW(3,lane) + b_n[lane];  // h_new
    }
}

extern "C" void kernel_launch(void* const* d_in, const int* in_sizes, int n_in,
                              void* d_out, int out_size, void* d_ws, size_t ws_size,
                              hipStream_t stream) {
    (void)in_sizes; (void)n_in; (void)out_size; (void)ws_size;
    const float* h    = (const float*)d_in[0];
    const float* x    = (const float*)d_in[1];
    const float* W_ew = (const float*)d_in[2];
    const float* b_ew = (const float*)d_in[3];
    const float* W_sa = (const float*)d_in[4];
    const float* W_es = (const float*)d_in[5];
    const float* b_es = (const float*)d_in[6];
    const float* W_c1 = (const float*)d_in[7];
    const float* b_c1 = (const float*)d_in[8];
    const float* W_c2 = (const float*)d_in[9];
    const float* b_c2 = (const float*)d_in[10];
    const float* W_n  = (const float*)d_in[11];
    const float* b_n  = (const float*)d_in[12];
    float* out = (float*)d_out;
    float* ws  = (float*)d_ws;

    proj_kernel<<<dim3(BN_/8), dim3(256), 0, stream>>>(h, W_ew, W_sa, W_es, ws);
    main_kernel<<<dim3(BN_), dim3(256), 0, stream>>>(h, x, b_ew, b_es, W_es, W_c1,
                                                     b_c1, W_c2, b_c2, W_n, b_n, ws, out);
}

// Round 10
// 154.205 us; speedup vs baseline: 1.0542x; 1.0106x over previous
//
#include <hip/hip_runtime.h>

#define B_ 4
#define N_ 512
#define F_ 64
#define H_ 64
#define K_ 64
#define BN_ (B_*N_)
#define EPS_ 1e-14f
#define TSC 2.8853900817779268f   // 2*log2(e): tanh(x) = 1 - 2/(2^(x*TSC)+1)

typedef __attribute__((ext_vector_type(8))) short short8;
typedef __attribute__((ext_vector_type(4))) float f32x4;
typedef __attribute__((ext_vector_type(2))) float f32x2;

__device__ __forceinline__ unsigned short f2bf(float f) {
    const unsigned u = __float_as_uint(f);
    return (unsigned short)((u + 0x7FFFu + ((u >> 16) & 1u)) >> 16);
}
__device__ __forceinline__ unsigned short cvt_bf16(float f) {
    unsigned r;
    asm("v_cvt_pk_bf16_f32 %0, %1, %1" : "=v"(r) : "v"(f));
    return (unsigned short)r;
}
__device__ __forceinline__ unsigned cvt_pk_bf16(float lo, float hi) {
    unsigned r;
    asm("v_cvt_pk_bf16_f32 %0, %1, %2" : "=v"(r) : "v"(lo), "v"(hi));
    return r;
}
__device__ __forceinline__ float exp2_raw(float x) {   // single v_exp_f32 (2^x)
    float r;
    asm("v_exp_f32 %0, %1" : "=v"(r) : "v"(x));
    return r;
}
__device__ __forceinline__ float lane_bcast(float v, int lane) {
    return __int_as_float(__builtin_amdgcn_readlane(__float_as_int(v), lane));
}
__device__ __forceinline__ float rcpf(float x) { return __builtin_amdgcn_rcpf(x); }
__device__ __forceinline__ float fast_silu(float x) {
    return x * rcpf(1.0f + __expf(-x));
}

// ws (floats): PJ2[BN][64][2] ({ew(pre-scaled by TSC),es} interleaved) |
//              PI_EW[BN*64] | PI_ES[BN*64] | PJSA[BN] | PISA[BN]
#define W_PJ2  0
#define W_PIEW (BN_*128)
#define W_PIES (BN_*128 + BN_*64)
#define W_PJSA (BN_*128 + 2*BN_*64)
#define W_PISA (BN_*128 + 2*BN_*64 + BN_)

__global__ __launch_bounds__(256) void proj_kernel(
    const float* __restrict__ h, const float* __restrict__ W_ew,
    const float* __restrict__ W_sa, const float* __restrict__ W_es,
    float* __restrict__ ws)
{
    const int tid  = threadIdx.x;
    const int w    = tid >> 6;
    const int lane = tid & 63;
    const int node0 = blockIdx.x * 8;

    __shared__ float sW_ew[128][64];   // W_ew[f][t], f in [0,128)
    __shared__ float sW_es[128][64];   // W_es[1+f][t]
    __shared__ float sW_sa[128];
    __shared__ float sh[8][64];

    #pragma unroll
    for (int it = 0; it < 32; ++it) {
        const int idx = it*256 + tid;
        sW_ew[idx>>6][idx&63] = W_ew[idx];
        sW_es[idx>>6][idx&63] = W_es[64 + idx];   // skip row 0 of W_es
    }
    if (tid < 128) sW_sa[tid] = W_sa[tid];
    #pragma unroll
    for (int it = 0; it < 2; ++it) {
        const int idx = it*256 + tid;
        sh[idx>>6][idx&63] = h[node0*F_ + idx];
    }
    __syncthreads();

    const int n0 = w*2;                 // two nodes per wave
    float jew0=0.f,iew0=0.f,jes0=0.f,ies0=0.f;
    float jew1=0.f,iew1=0.f,jes1=0.f,ies1=0.f;
    #pragma unroll 8
    for (int f = 0; f < 64; ++f) {
        const float wje = sW_ew[f][lane],    wie = sW_ew[64+f][lane];
        const float wjs = sW_es[f][lane],    wis = sW_es[64+f][lane];
        const float h0  = sh[n0][f],         h1  = sh[n0+1][f];
        jew0 = fmaf(h0, wje, jew0);  iew0 = fmaf(h0, wie, iew0);
        jes0 = fmaf(h0, wjs, jes0);  ies0 = fmaf(h0, wis, ies0);
        jew1 = fmaf(h1, wje, jew1);  iew1 = fmaf(h1, wie, iew1);
        jes1 = fmaf(h1, wjs, jes1);  ies1 = fmaf(h1, wis, ies1);
    }
    // W_sa projections: lane-parallel over f, shuffle-reduce
    float p0 = sh[n0][lane]   * sW_sa[lane];
    float q0 = sh[n0][lane]   * sW_sa[64+lane];
    float p1 = sh[n0+1][lane] * sW_sa[lane];
    float q1 = sh[n0+1][lane] * sW_sa[64+lane];
    #pragma unroll
    for (int m = 32; m >= 1; m >>= 1) {
        p0 += __shfl_xor(p0, m, 64);  q0 += __shfl_xor(q0, m, 64);
        p1 += __shfl_xor(p1, m, 64);  q1 += __shfl_xor(q1, m, 64);
    }

    const int g0 = node0 + n0;
    const int g1 = g0 + 1;
    ws[W_PJ2 + (size_t)g0*128 + lane*2 + 0] = jew0 * TSC;  // pre-scaled for tanh
    ws[W_PJ2 + (size_t)g0*128 + lane*2 + 1] = jes0;
    ws[W_PJ2 + (size_t)g1*128 + lane*2 + 0] = jew1 * TSC;
    ws[W_PJ2 + (size_t)g1*128 + lane*2 + 1] = jes1;
    ws[W_PIEW + g0*K_ + lane] = iew0;
    ws[W_PIEW + g1*K_ + lane] = iew1;
    ws[W_PIES + g0*H_ + lane] = ies0;
    ws[W_PIES + g1*H_ + lane] = ies1;
    if (lane == 0) {
        ws[W_PJSA + g0] = p0;  ws[W_PISA + g0] = q0;
        ws[W_PJSA + g1] = p1;  ws[W_PISA + g1] = q1;
    }
}

// R10: CONSOLIDATION — exact R4 main (measured best: 84.6-85.0 us) + R6 proj.
// R4 vs R6/R9 lesson: s_bw-in-LDS (phase-C inner-loop b64 reads) and the
// epilogue-alias barrier cost ~2 us; pk_add another ~2; neither enabled
// anything (minw=6 spills regardless).  bc1v/wc2v stay in regs (8 VGPRs,
// fits the 48-reg grant at minw=5); epilogue uses dedicated LDS.
// Ledger: minw=6 budget 85 -> arch 40 -> spill; minw=5 budget 102 -> arch 48,
// no spill, 5 waves/SIMD.  LDS 27648 -> 5 blocks/CU (138 KB).  Both limits
// coincide at 5.  Spill tripwire: FETCH ~5.8 MB.
__global__ __launch_bounds__(256, 5) void main_kernel(
    const float* __restrict__ h, const float* __restrict__ x,
    const float* __restrict__ b_ew, const float* __restrict__ b_es,
    const float* __restrict__ W_es, const float* __restrict__ W_c1,
    const float* __restrict__ b_c1, const float* __restrict__ W_c2,
    const float* __restrict__ b_c2, const float* __restrict__ W_n,
    const float* __restrict__ b_n,
    const float* __restrict__ ws, float* __restrict__ out)
{
    const int bi   = blockIdx.x;          // b*N + i
    const int b    = bi >> 9;
    const int base = b * N_;
    const int tid  = threadIdx.x;
    const int w    = tid >> 6;            // wave 0..3
    const int lane = tid & 63;
    const int quad = lane >> 4;
    const int l16  = lane & 15;

    __shared__ unsigned short he_buf[4][16][72];  // bf16 he subtile (16 j rows)
    __shared__ float sdA[4][64][4];       // {v0,v1,v2,filt} per j
    __shared__ float coord_buf[4][64];
    __shared__ float s_att[3][4][64];
    __shared__ float s_hea[4][64];
    __shared__ float s_misc[4][4];        // per wave: sum_e, xa0, xa1, xa2
    __shared__ float s_concat[192];
    // W_c1^T as bf16, XOR-swizzled: element (k,col) at byte col*128 + (2k ^ ((col&7)<<4))
    __shared__ unsigned short WT[64*64];

    // ---- stage W_c1 into LDS (shared by all 4 waves; frees 32 VGPRs/wave) ----
    {
        const int col = tid & 63;
        const int k0  = (tid >> 6) * 16;
        const unsigned swz = (col & 7) << 4;
        #pragma unroll
        for (int m = 0; m < 8; ++m) {
            const int k = k0 + 2*m;
            const float f0 = W_c1[k*H_ + col];
            const float f1 = W_c1[(k+1)*H_ + col];
            *(unsigned*)((char*)WT + (col*128 + ((2*k) ^ swz))) = cvt_pk_bf16(f0, f1);
        }
    }

    const float pi_ew_t = (ws[W_PIEW + bi*K_ + lane] + b_ew[lane]) * TSC;
    const float pi_es_t = ws[W_PIES + bi*H_ + lane] + b_es[lane];
    const float pisa    = ws[W_PISA + bi];
    const float xi0 = x[bi*3+0], xi1 = x[bi*3+1], xi2 = x[bi*3+2];
    const float wes0_t = W_es[lane];
    const float bc2    = b_c2[0];

    float bc1v[4], wc2v[4];
    #pragma unroll
    for (int nt = 0; nt < 4; ++nt) {
        bc1v[nt] = b_c1[nt*16 + l16];
        wc2v[nt] = W_c2[nt*16 + l16];
    }

    // per-lane swizzled byte offsets of the two B-fragments (kc=0,1) in WT
    const unsigned swzl = (l16 & 7) << 4;
    const unsigned offB0 = (unsigned)l16*128 + (((unsigned)quad*16) ^ swzl);
    const unsigned offB1 = (unsigned)l16*128 + ((64u + (unsigned)quad*16) ^ swzl);

    __syncthreads();   // WT ready

    float att0=0.f, att1=0.f, att2=0.f, hea=0.f, sume=0.f;
    float xa0=0.f, xa1=0.f, xa2=0.f;

    for (int c = 0; c < 2; ++c) {
        const int j0 = (w*2 + c) * 64;

        // ---- phase A: per-j scalars (lane = jj over 64) ----
        float esem, d0, d1, d2;
        {
            const int gj = base + j0 + lane;
            d0 = x[gj*3+0] - xi0;
            d1 = x[gj*3+1] - xi1;
            d2 = x[gj*3+2] - xi2;
            const float d2s = fmaf(d0,d0, fmaf(d1,d1, d2*d2));
            const float nrm = sqrtf(d2s + EPS_);
            const float e   = __expf(nrm);
            sume += e;
            const float filt = rcpf(nrm + 0.1f);
            const float inv  = rcpf(fmaf(nrm, nrm, EPS_));
            const float sv   = ws[W_PJSA + gj] + pisa;
            const float sem  = (sv >= 0.f) ? sv : 0.01f*sv;
            esem = e * sem;
            f32x4 p0 = { d0*inv, d1*inv, d2*inv, filt };
            *(f32x4*)&sdA[w][lane][0] = p0;
        }

        // four 16-j subchunks: phase B fills he subtile, phase C MFMAs it
        #pragma unroll
        for (int s = 0; s < 4; ++s) {
            const int sj = s*16;
            const float* pjp = ws + W_PJ2 + (size_t)(base + j0 + sj)*128 + lane*2;
            #pragma unroll 4
            for (int jj = 0; jj < 16; ++jj) {
                const f32x2 pj = *(const f32x2*)(pjp + (size_t)jj*128);
                const f32x4 p0 = *(const f32x4*)&sdA[w][sj + jj][0];   // broadcast
                const float esem_s = lane_bcast(esem, sj + jj);
                const float pre = fmaf(p0.w, wes0_t, pj.y + pi_es_t);
                const float he  = fast_silu(pre);
                hea = fmaf(esem_s, he, hea);
                he_buf[w][jj][lane] = cvt_bf16(he);
                // tanh with pre-scaled argument: 1 - 2/(2^(x') + 1)
                const float ewt = fmaf(-2.0f, rcpf(exp2_raw(pj.x + pi_ew_t) + 1.0f), 1.0f);
                att0 = fmaf(ewt, p0.x, att0);
                att1 = fmaf(ewt, p0.y, att1);
                att2 = fmaf(ewt, p0.z, att2);
            }

            // ---- phase C: coord MLP via MFMA on the 16-row subtile ----
            {
                const short8 a0 = *(const short8*)&he_buf[w][l16][quad*8];
                const short8 a1 = *(const short8*)&he_buf[w][l16][32 + quad*8];
                float rs0=0.f, rs1=0.f, rs2=0.f, rs3=0.f;
                #pragma unroll
                for (int nt = 0; nt < 4; ++nt) {
                    const short8 b0 = *(const short8*)((const char*)WT + (nt*2048 + offB0));
                    const short8 b1 = *(const short8*)((const char*)WT + (nt*2048 + offB1));
                    f32x4 acc = {0.f, 0.f, 0.f, 0.f};
                    acc = __builtin_amdgcn_mfma_f32_16x16x32_bf16(a0, b0, acc, 0, 0, 0);
                    acc = __builtin_amdgcn_mfma_f32_16x16x32_bf16(a1, b1, acc, 0, 0, 0);
                    rs0 += fast_silu(acc[0] + bc1v[nt]) * wc2v[nt];
                    rs1 += fast_silu(acc[1] + bc1v[nt]) * wc2v[nt];
                    rs2 += fast_silu(acc[2] + bc1v[nt]) * wc2v[nt];
                    rs3 += fast_silu(acc[3] + bc1v[nt]) * wc2v[nt];
                }
                #pragma unroll
                for (int m = 1; m <= 8; m <<= 1) {      // reduce over cols (l16)
                    rs0 += __shfl_xor(rs0, m, 64);
                    rs1 += __shfl_xor(rs1, m, 64);
                    rs2 += __shfl_xor(rs2, m, 64);
                    rs3 += __shfl_xor(rs3, m, 64);
                }
                if (l16 == 0) {
                    f32x4 cv = { rs0 + bc2, rs1 + bc2, rs2 + bc2, rs3 + bc2 };
                    *(f32x4*)&coord_buf[w][sj + quad*4] = cv;
                }
            }
        }

        // ---- phase D: xa += d * coord (lane = jj over 64) ----
        {
            const float cj = coord_buf[w][lane];
            xa0 = fmaf(d0, cj, xa0);
            xa1 = fmaf(d1, cj, xa1);
            xa2 = fmaf(d2, cj, xa2);
        }
    }

    // wave-level reduce of j-lane partials
    #pragma unroll
    for (int m = 32; m >= 1; m >>= 1) {
        sume += __shfl_xor(sume, m, 64);
        xa0  += __shfl_xor(xa0,  m, 64);
        xa1  += __shfl_xor(xa1,  m, 64);
        xa2  += __shfl_xor(xa2,  m, 64);
    }
    s_att[0][w][lane] = att0;
    s_att[1][w][lane] = att1;
    s_att[2][w][lane] = att2;
    s_hea[w][lane]    = hea;
    if (lane == 0) {
        s_misc[w][0] = sume; s_misc[w][1] = xa0; s_misc[w][2] = xa1; s_misc[w][3] = xa2;
    }
    __syncthreads();

    if (w == 0) {
        const float a0 = s_att[0][0][lane]+s_att[0][1][lane]+s_att[0][2][lane]+s_att[0][3][lane];
        const float a1 = s_att[1][0][lane]+s_att[1][1][lane]+s_att[1][2][lane]+s_att[1][3][lane];
        const float a2 = s_att[2][0][lane]+s_att[2][1][lane]+s_att[2][2][lane]+s_att[2][3][lane];
        const float hg = s_hea[0][lane]+s_hea[1][lane]+s_hea[2][lane]+s_hea[3][lane];
        const float se = s_misc[0][0]+s_misc[1][0]+s_misc[2][0]+s_misc[3][0];
        const float attn = sqrtf(fmaf(a0,a0, fmaf(a1,a1, a2*a2)) + EPS_);
        s_concat[lane]       = h[bi*F_ + lane];
        s_concat[64 + lane]  = hg * rcpf(se);
        s_concat[128 + lane] = attn;
    }
    if (tid < 3) {
        const float xat = s_misc[0][1+tid]+s_misc[1][1+tid]+s_misc[2][1+tid]+s_misc[3][1+tid];
        out[(size_t)BN_*H_ + bi*3 + tid] = x[bi*3+tid] + xat;       // x_new
    }
    __syncthreads();

    // output GEMV split across 4 waves (48 rows each); partials go into
    // s_hnew aliased onto sdA (dead after the main loop, fenced by barriers)
    float (*s_hnew)[64] = (float (*)[64])&sdA[0][0][0];
    {
        float acc = 0.f;
        const int m0 = w * 48;
        #pragma unroll 8
        for (int m = m0; m < m0 + 48; ++m)
            acc = fmaf(s_concat[m], W_n[m*H_ + lane], acc);
        s_hnew[w][lane] = acc;
    }
    __syncthreads();
    if (w == 0) {
        out[bi*H_ + lane] = s_hnew[0][lane] + s_hnew[1][lane]
                          + s_hnew[2][lane] + s_hnew[3][lane] + b_n[lane];  // h_new
    }
}

extern "C" void kernel_launch(void* const* d_in, const int* in_sizes, int n_in,
                              void* d_out, int out_size, void* d_ws, size_t ws_size,
                              hipStream_t stream) {
    (void)in_sizes; (void)n_in; (void)out_size; (void)ws_size;
    const float* h    = (const float*)d_in[0];
    const float* x    = (const float*)d_in[1];
    const float* W_ew = (const float*)d_in[2];
    const float* b_ew = (const float*)d_in[3];
    const float* W_sa = (const float*)d_in[4];
    const float* W_es = (const float*)d_in[5];
    const float* b_es = (const float*)d_in[6];
    const float* W_c1 = (const float*)d_in[7];
    const float* b_c1 = (const float*)d_in[8];
    const float* W_c2 = (const float*)d_in[9];
    const float* b_c2 = (const float*)d_in[10];
    const float* W_n  = (const float*)d_in[11];
    const float* b_n  = (const float*)d_in[12];
    float* out = (float*)d_out;
    float* ws  = (float*)d_ws;

    proj_kernel<<<dim3(BN_/8), dim3(256), 0, stream>>>(h, W_ew, W_sa, W_es, ws);
    main_kernel<<<dim3(BN_), dim3(256), 0, stream>>>(h, x, b_ew, b_es, W_es, W_c1,
                                                     b_c1, W_c2, b_c2, W_n, b_n, ws, out);
}